// Round 1
// baseline (526.830 us; speedup 1.0000x reference)
//
#include <hip/hip_runtime.h>

#define DIM 128
#define KK 3
#define NPB 8  // nodes per block in support kernel

// Transpose weight [D_IN][D_OUT][K] -> Wt[K][D_IN][D_OUT] so support GEMM
// reads are coalesced (consecutive d threads -> consecutive addresses).
__global__ void GraphConv_wt_kernel(const float* __restrict__ w, float* __restrict__ wt) {
    int idx = blockIdx.x * blockDim.x + threadIdx.x;
    if (idx >= DIM * DIM * KK) return;
    int k = idx % KK;
    int d = (idx / KK) % DIM;
    int i = idx / (KK * DIM);
    wt[((size_t)k * DIM + i) * DIM + d] = w[idx];
}

// support[n][k][d] = sum_i x[n][i] * W[i][d][k]
// One 128-thread block computes NPB nodes; x rows staged in LDS, W reads
// (L2-resident, 196 KB total) amortized across NPB nodes.
__global__ __launch_bounds__(128) void GraphConv_support_kernel(
    const float* __restrict__ x, const float* __restrict__ wt,
    float* __restrict__ sup, int n_nodes) {
    __shared__ float xs[NPB * DIM];
    int t = threadIdx.x;          // output feature d
    int n0 = blockIdx.x * NPB;

    for (int j = 0; j < NPB; ++j) {
        int n = n0 + j;
        xs[j * DIM + t] = (n < n_nodes) ? x[(size_t)n * DIM + t] : 0.0f;
    }
    __syncthreads();

    float acc[NPB][KK];
#pragma unroll
    for (int j = 0; j < NPB; ++j)
#pragma unroll
        for (int k = 0; k < KK; ++k) acc[j][k] = 0.0f;

    for (int i = 0; i < DIM; ++i) {
        float w0 = wt[(0 * DIM + i) * DIM + t];
        float w1 = wt[(1 * DIM + i) * DIM + t];
        float w2 = wt[(2 * DIM + i) * DIM + t];
#pragma unroll
        for (int j = 0; j < NPB; ++j) {
            float xi = xs[j * DIM + i];  // LDS broadcast (same addr all lanes) - free
            acc[j][0] = fmaf(xi, w0, acc[j][0]);
            acc[j][1] = fmaf(xi, w1, acc[j][1]);
            acc[j][2] = fmaf(xi, w2, acc[j][2]);
        }
    }

    for (int j = 0; j < NPB; ++j) {
        int n = n0 + j;
        if (n < n_nodes) {
            float* s = sup + (size_t)n * (KK * DIM);
            s[0 * DIM + t] = acc[j][0];
            s[1 * DIM + t] = acc[j][1];
            s[2 * DIM + t] = acc[j][2];
        }
    }
}

// out[n][d] = bias[d]  (d_out is poisoned 0xAA before every launch)
__global__ void GraphConv_bias_kernel(const float* __restrict__ bias,
                                      float* __restrict__ out, int total) {
    int i = blockIdx.x * blockDim.x + threadIdx.x;
    if (i < total) out[i] = bias[i & (DIM - 1)];
}

// Per edge e: out[row] += sum_k TT[e,k] * sup[col][k][:]
// 128 threads per edge (2 edges per 256-thread block), f32 atomics.
__global__ __launch_bounds__(256) void GraphConv_scatter_kernel(
    const int* __restrict__ eidx, const float* __restrict__ TT,
    const float* __restrict__ sup, float* __restrict__ out, int E) {
    int t = threadIdx.x & (DIM - 1);
    int sub = threadIdx.x >> 7;
    long long e = (long long)blockIdx.x * 2 + sub;
    long long stride = (long long)gridDim.x * 2;
    for (; e < E; e += stride) {
        int row = eidx[e];
        int col = eidx[(size_t)E + e];
        float t0 = TT[e * 3 + 0];
        float t1 = TT[e * 3 + 1];
        float t2 = TT[e * 3 + 2];
        const float* s = sup + (size_t)col * (KK * DIM);
        float v = fmaf(t0, s[t], fmaf(t1, s[DIM + t], t2 * s[2 * DIM + t]));
        atomicAdd(&out[(size_t)row * DIM + t], v);
    }
}

extern "C" void kernel_launch(void* const* d_in, const int* in_sizes, int n_in,
                              void* d_out, int out_size, void* d_ws, size_t ws_size,
                              hipStream_t stream) {
    const float* x    = (const float*)d_in[0];
    const float* TT   = (const float*)d_in[1];
    const float* w    = (const float*)d_in[2];
    const float* bias = (const float*)d_in[3];
    const int*   eidx = (const int*)d_in[4];
    float* out = (float*)d_out;

    int n_nodes = in_sizes[0] / DIM;   // 50000
    int E       = in_sizes[1] / KK;    // 800000

    // Workspace layout: [ support: n_nodes*K*D floats | Wt: K*D*D floats ]
    float* sup = (float*)d_ws;
    float* wt  = sup + (size_t)n_nodes * KK * DIM;

    GraphConv_wt_kernel<<<(DIM * DIM * KK + 255) / 256, 256, 0, stream>>>(w, wt);

    GraphConv_support_kernel<<<(n_nodes + NPB - 1) / NPB, DIM, 0, stream>>>(
        x, wt, sup, n_nodes);

    int total = n_nodes * DIM;
    GraphConv_bias_kernel<<<(total + 255) / 256, 256, 0, stream>>>(bias, out, total);

    int nblk = (E + 1) / 2;
    GraphConv_scatter_kernel<<<nblk, 256, 0, stream>>>(eidx, TT, sup, out, E);
}